// Round 11
// baseline (351.771 us; speedup 1.0000x reference)
//
#include <hip/hip_runtime.h>

constexpr int HID = 64;
constexpr int BSHIFT = 9;            // bucket = dst >> 9 (512 nodes per bucket)
constexpr int BSIZE = 1 << BSHIFT;   // 512
constexpr int NBMAX = 256;           // max buckets (N=100k -> 196)
constexpr int EPB = 4096;            // edges per k_part block

// Merged init + weight-prep: gL[k][j] = g[k]*L[k][j]; cj[j] = lb[j] + sum_k be[k]*L[k][j].
__global__ void k_init_prep(float* __restrict__ out, int d, int* __restrict__ bsize, int nb,
                            const float* __restrict__ g1, const float* __restrict__ be1,
                            const float* __restrict__ L1, const float* __restrict__ lb1,
                            const float* __restrict__ g2, const float* __restrict__ be2,
                            const float* __restrict__ L2, const float* __restrict__ lb2,
                            const float* __restrict__ g3, const float* __restrict__ be3,
                            const float* __restrict__ L3, const float* __restrict__ lb3,
                            float* __restrict__ gL1, float* __restrict__ cj1,
                            float* __restrict__ gL2, float* __restrict__ cj2,
                            float* __restrict__ gL3, float* __restrict__ cj3) {
  int t = blockIdx.x * blockDim.x + threadIdx.x;
  if (t < d) out[t] = 0.f;
  if (t < nb) bsize[t] = 0;
  if (t < 768) gL1[t] = g1[t / 12] * L1[t];
  else if (t < 768 + 1536) { int i = t - 768;  gL2[i] = g2[i / 24] * L2[i]; }
  else if (t < 2304 + 3072) { int i = t - 2304; gL3[i] = g3[i / 48] * L3[i]; }
  else if (t < 5376 + 84) {
    int i = t - 5376;
    if (i < 12) {
      float s = lb1[i];
      for (int k = 0; k < HID; ++k) s += be1[k] * L1[k * 12 + i];
      cj1[i] = s;
    } else if (i < 36) {
      int j = i - 12;
      float s = lb2[j];
      for (int k = 0; k < HID; ++k) s += be2[k] * L2[k * 24 + j];
      cj2[j] = s;
    } else {
      int j = i - 36;
      float s = lb3[j];
      for (int k = 0; k < HID; ++k) s += be3[k] * L3[k * 48 + j];
      cj3[j] = s;
    }
  }
}

// Bucket histogram: LDS-aggregated, ~grid*196 global atomics total.
__global__ __launch_bounds__(256)
void k_hist(const int* __restrict__ dst, int E, int* __restrict__ bsize) {
  __shared__ int l[NBMAX];
  int t = threadIdx.x;
  for (int i = t; i < NBMAX; i += 256) l[i] = 0;
  __syncthreads();
  int nq = E >> 2;
  const int4* d4 = (const int4*)dst;
  for (int q = blockIdx.x * 256 + t; q < nq; q += gridDim.x * 256) {
    int4 d = d4[q];
    atomicAdd(&l[d.x >> BSHIFT], 1);
    atomicAdd(&l[d.y >> BSHIFT], 1);
    atomicAdd(&l[d.z >> BSHIFT], 1);
    atomicAdd(&l[d.w >> BSHIFT], 1);
  }
  if (blockIdx.x == 0) {
    for (int e = (nq << 2) + t; e < E; e += 256) atomicAdd(&l[dst[e] >> BSHIFT], 1);
  }
  __syncthreads();
  for (int i = t; i < NBMAX; i += 256) if (l[i]) atomicAdd(&bsize[i], l[i]);
}

// Scan 196 bucket sizes -> bucket_base / bucket_cur; sentinels.
__global__ __launch_bounds__(256)
void k_bscan(const int* __restrict__ bsize, int nbk, int E, int N,
             int* __restrict__ bucket_base, int* __restrict__ bucket_cur,
             int* __restrict__ row_start) {
  __shared__ int sm[256];
  int t = threadIdx.x;
  int v = (t < nbk) ? bsize[t] : 0;
  sm[t] = v;
  __syncthreads();
  for (int off = 1; off < 256; off <<= 1) {
    int u = (t >= off) ? sm[t - off] : 0;
    __syncthreads();
    sm[t] += u;
    __syncthreads();
  }
  if (t < nbk) {
    int base = sm[t] - v;
    bucket_base[t] = base;
    bucket_cur[t] = base;
  }
  if (t == 0) { bucket_base[nbk] = E; row_start[N] = E; }
}

// Partition edges into dst-buckets; entry packed as (src<<9)|(dst&511) -> 4B.
__global__ __launch_bounds__(256)
void k_part(const int* __restrict__ src, const int* __restrict__ dst, int E,
            int* __restrict__ bucket_cur, unsigned* __restrict__ part) {
  __shared__ int lcnt[NBMAX];
  __shared__ int lcur[NBMAX];
  int t = threadIdx.x;
  int base = blockIdx.x * EPB;
  for (int i = t; i < NBMAX; i += 256) lcnt[i] = 0;
  __syncthreads();
  bool full = (base + EPB) <= E;
  int4 sv[4], dv[4];
  if (full) {
    const int4* src4 = (const int4*)src;
    const int4* dst4 = (const int4*)dst;
    #pragma unroll
    for (int u = 0; u < 4; ++u) {
      int q = (base >> 2) + u * 256 + t;
      sv[u] = src4[q];
      dv[u] = dst4[q];
    }
    #pragma unroll
    for (int u = 0; u < 4; ++u) {
      atomicAdd(&lcnt[dv[u].x >> BSHIFT], 1);
      atomicAdd(&lcnt[dv[u].y >> BSHIFT], 1);
      atomicAdd(&lcnt[dv[u].z >> BSHIFT], 1);
      atomicAdd(&lcnt[dv[u].w >> BSHIFT], 1);
    }
  } else {
    for (int u = 0; u < 16; ++u) {
      int e = base + u * 256 + t;
      if (e < E) atomicAdd(&lcnt[dst[e] >> BSHIFT], 1);
    }
  }
  __syncthreads();
  for (int i = t; i < NBMAX; i += 256)
    lcur[i] = lcnt[i] ? atomicAdd(&bucket_cur[i], lcnt[i]) : 0;
  __syncthreads();
  if (full) {
    #pragma unroll
    for (int u = 0; u < 4; ++u) {
      int pos;
      pos = atomicAdd(&lcur[dv[u].x >> BSHIFT], 1);
      part[pos] = ((unsigned)sv[u].x << BSHIFT) | ((unsigned)dv[u].x & (BSIZE - 1));
      pos = atomicAdd(&lcur[dv[u].y >> BSHIFT], 1);
      part[pos] = ((unsigned)sv[u].y << BSHIFT) | ((unsigned)dv[u].y & (BSIZE - 1));
      pos = atomicAdd(&lcur[dv[u].z >> BSHIFT], 1);
      part[pos] = ((unsigned)sv[u].z << BSHIFT) | ((unsigned)dv[u].z & (BSIZE - 1));
      pos = atomicAdd(&lcur[dv[u].w >> BSHIFT], 1);
      part[pos] = ((unsigned)sv[u].w << BSHIFT) | ((unsigned)dv[u].w & (BSIZE - 1));
    }
  } else {
    for (int u = 0; u < 16; ++u) {
      int e = base + u * 256 + t;
      if (e < E) {
        int s = src[e], d = dst[e];
        int pos = atomicAdd(&lcur[d >> BSHIFT], 1);
        part[pos] = ((unsigned)s << BSHIFT) | ((unsigned)d & (BSIZE - 1));
      }
    }
  }
}

// Per-bucket: LDS per-node histogram + LDS scan -> row_start/dinv/y1, then
// LDS-cursor scatter -> csr_src. Zero per-node GLOBAL atomics.
__global__ __launch_bounds__(512)
void k_bucket(const unsigned* __restrict__ part, const int* __restrict__ bucket_base,
              const float* __restrict__ x, int N,
              int* __restrict__ row_start, float* __restrict__ dinv,
              float* __restrict__ y1, int* __restrict__ csr_src) {
  __shared__ int hist[BSIZE];
  __shared__ int cur[BSIZE];
  int b = blockIdx.x;
  int t = threadIdx.x;
  int base = bucket_base[b];
  int end = bucket_base[b + 1];
  hist[t] = 0;
  __syncthreads();
  for (int e = base + t; e < end; e += BSIZE)
    atomicAdd(&hist[part[e] & (BSIZE - 1)], 1);
  __syncthreads();
  int c = hist[t];
  for (int off = 1; off < BSIZE; off <<= 1) {
    int u = (t >= off) ? hist[t - off] : 0;
    __syncthreads();
    hist[t] += u;
    __syncthreads();
  }
  int gpos = base + hist[t] - c;  // exclusive prefix + bucket base
  cur[t] = gpos;
  int node = (b << BSHIFT) + t;
  if (node < N) {
    row_start[node] = gpos;
    float di = rsqrtf((float)(c + 1));
    dinv[node] = di;
    const float* xr = x + (size_t)node * 6;
    float4* yp = (float4*)(y1 + (size_t)node * 8);
    yp[0] = make_float4(xr[0] * di, xr[1] * di, xr[2] * di, xr[3] * di);
    yp[1] = make_float4(xr[4] * di, xr[5] * di, 0.f, 0.f);
  }
  __syncthreads();
  for (int e = base + t; e < end; e += BSIZE) {
    unsigned u = part[e];
    int pos = atomicAdd(&cur[u & (BSIZE - 1)], 1);
    csr_src[pos] = (int)(u >> BSHIFT);
  }
}

// Gather-aggregate of pre-scaled features y [N][F] (F=8/16/32 padded).
// U*C = 32 edges issued per round -> deg<=32 rows (>99.9%) finish in ONE
// latency round. Clamped tail loads hit the same cache line (same s, f).
template<int F, int LOGF, int U>
__global__ __launch_bounds__(256)
void k_agg(const float* __restrict__ y, const int* __restrict__ row_start,
           const int* __restrict__ csr, float* __restrict__ agg, int N) {
  constexpr int C = 64 / F;
  int wid = (blockIdx.x * blockDim.x + threadIdx.x) >> 6;
  if (wid >= N) return;
  int lane = threadIdx.x & 63;
  int es = lane >> LOGF;
  int f = lane & (F - 1);
  int e0 = row_start[wid], e1 = row_start[wid + 1];
  float acc = 0.f;
  for (int e = e0 + es; e < e1; e += U * C) {
    float v[U];
    #pragma unroll
    for (int u = 0; u < U; ++u) {
      int ee = e + u * C;
      int ec = min(ee, e1 - 1);
      int s = csr[ec];
      float val = y[(size_t)s * F + f];
      v[u] = (ee < e1) ? val : 0.f;
    }
    #pragma unroll
    for (int u = 0; u < U; ++u) acc += v[u];
  }
  #pragma unroll
  for (int m = F; m < 64; m <<= 1) acc += __shfl_xor(acc, m);
  if (lane < F) {
    acc += y[(size_t)wid * F + f];  // self loop (y already *dinv[self])
    agg[(size_t)wid * F + f] = acc;
  }
}

// Fused per-row epilogue (layers 1-2): h = relu(dinv*(agg@W) + b); LN in-reg;
// out = relu(inv*(d@gL) + cj) * dinv (pre-scaled for next gather).
template<int DIN, int DOUT, int FIN, int FOUT>
__global__ __launch_bounds__(64)
void k_fpost(const float* __restrict__ agg, const float* __restrict__ dinv,
             const float* __restrict__ W, const float* __restrict__ bb,
             const float* __restrict__ gL, const float* __restrict__ cj,
             float* __restrict__ yout, int N) {
  int row = blockIdx.x * 64 + threadIdx.x;
  bool act = row < N;
  int r = act ? row : N - 1;
  const float4* ap = (const float4*)(agg + (size_t)r * FIN);
  float di = dinv[r];
  float h[HID];
  #pragma unroll
  for (int j = 0; j < HID; ++j) h[j] = 0.f;
  // interleave agg chunks with GEMM: only 4 a-floats live at once
  #pragma unroll
  for (int c = 0; c < DIN / 4; ++c) {
    float4 t4 = ap[c];
    float av[4] = {t4.x, t4.y, t4.z, t4.w};
    #pragma unroll
    for (int u = 0; u < 4; ++u) {
      float v = av[u];
      int k = 4 * c + u;
      #pragma unroll
      for (int j = 0; j < HID; ++j) h[j] = fmaf(v, W[k * HID + j], h[j]);
    }
  }
  if constexpr (DIN % 4 != 0) {
    // DIN=6: tail 2 elements
    float2 t2 = ((const float2*)ap)[DIN / 2 - 1];
    float av[2] = {t2.x, t2.y};
    #pragma unroll
    for (int u = 0; u < 2; ++u) {
      float v = av[u];
      int k = (DIN / 4) * 4 + u;
      #pragma unroll
      for (int j = 0; j < HID; ++j) h[j] = fmaf(v, W[k * HID + j], h[j]);
    }
  }
  float s0 = 0.f, s1 = 0.f, s2 = 0.f, s3 = 0.f;
  #pragma unroll
  for (int k = 0; k < HID; k += 4) {
    h[k]     = fmaxf(fmaf(h[k],     di, bb[k]),     0.f); s0 += h[k];
    h[k + 1] = fmaxf(fmaf(h[k + 1], di, bb[k + 1]), 0.f); s1 += h[k + 1];
    h[k + 2] = fmaxf(fmaf(h[k + 2], di, bb[k + 2]), 0.f); s2 += h[k + 2];
    h[k + 3] = fmaxf(fmaf(h[k + 3], di, bb[k + 3]), 0.f); s3 += h[k + 3];
  }
  float mu = ((s0 + s1) + (s2 + s3)) * (1.f / 64.f);
  float q0 = 0.f, q1 = 0.f, q2 = 0.f, q3 = 0.f;
  #pragma unroll
  for (int k = 0; k < HID; k += 4) {
    float d0 = h[k] - mu, d1 = h[k + 1] - mu, d2 = h[k + 2] - mu, d3 = h[k + 3] - mu;
    h[k] = d0; h[k + 1] = d1; h[k + 2] = d2; h[k + 3] = d3;
    q0 = fmaf(d0, d0, q0); q1 = fmaf(d1, d1, q1);
    q2 = fmaf(d2, d2, q2); q3 = fmaf(d3, d3, q3);
  }
  float inv = rsqrtf(((q0 + q1) + (q2 + q3)) * (1.f / 64.f) + 1e-5f);
  float acc[DOUT];
  #pragma unroll
  for (int j = 0; j < DOUT; ++j) acc[j] = 0.f;
  #pragma unroll
  for (int k = 0; k < HID; ++k) {
    float d = h[k];
    #pragma unroll
    for (int j = 0; j < DOUT; ++j) acc[j] = fmaf(d, gL[k * DOUT + j], acc[j]);
  }
  if (act) {
    float4* op = (float4*)(yout + (size_t)row * FOUT);
    #pragma unroll
    for (int c = 0; c < FOUT / 4; ++c) {
      float o[4];
      #pragma unroll
      for (int u = 0; u < 4; ++u) {
        int j = 4 * c + u;
        o[u] = (j < DOUT) ? fmaxf(fmaf(inv, acc[j], cj[j]), 0.f) * di : 0.f;
      }
      op[c] = make_float4(o[0], o[1], o[2], o[3]);
    }
  }
}

// Layer-3 epilogue fused with global column-max. Restructured vs r8 to avoid
// scratch spill (was VGPR=60 with 145 live floats): agg consumed in float4
// chunks; outputs in 3 j-blocks of 16 (acc[16] live, not o[48]).
// Peak live set ~ h[64]+acc[16]+misc ~ 95 VGPR.
__global__ __launch_bounds__(256, 1)
void k_fpost3(const float* __restrict__ agg, const float* __restrict__ dinv,
              const float* __restrict__ W, const float* __restrict__ bb,
              const float* __restrict__ gL, const float* __restrict__ cj,
              float* __restrict__ dout, int N) {
  constexpr int DIN = 24, DOUT = 48;
  __shared__ int lmax[DOUT];
  int t = threadIdx.x;
  if (t < DOUT) lmax[t] = 0;
  __syncthreads();
  int row = blockIdx.x * 256 + t;
  int r = min(row, N - 1);  // tail duplicates re-contribute a real row: max-safe
  const float4* ap = (const float4*)(agg + (size_t)r * 32);
  float di = dinv[r];
  float h[HID];
  #pragma unroll
  for (int j = 0; j < HID; ++j) h[j] = 0.f;
  #pragma unroll
  for (int c = 0; c < DIN / 4; ++c) {
    float4 t4 = ap[c];
    float av[4] = {t4.x, t4.y, t4.z, t4.w};
    #pragma unroll
    for (int u = 0; u < 4; ++u) {
      float v = av[u];
      int k = 4 * c + u;
      #pragma unroll
      for (int j = 0; j < HID; ++j) h[j] = fmaf(v, W[k * HID + j], h[j]);
    }
  }
  float s0 = 0.f, s1 = 0.f, s2 = 0.f, s3 = 0.f;
  #pragma unroll
  for (int k = 0; k < HID; k += 4) {
    h[k]     = fmaxf(fmaf(h[k],     di, bb[k]),     0.f); s0 += h[k];
    h[k + 1] = fmaxf(fmaf(h[k + 1], di, bb[k + 1]), 0.f); s1 += h[k + 1];
    h[k + 2] = fmaxf(fmaf(h[k + 2], di, bb[k + 2]), 0.f); s2 += h[k + 2];
    h[k + 3] = fmaxf(fmaf(h[k + 3], di, bb[k + 3]), 0.f); s3 += h[k + 3];
  }
  float mu = ((s0 + s1) + (s2 + s3)) * (1.f / 64.f);
  float q0 = 0.f, q1 = 0.f, q2 = 0.f, q3 = 0.f;
  #pragma unroll
  for (int k = 0; k < HID; k += 4) {
    float d0 = h[k] - mu, d1 = h[k + 1] - mu, d2 = h[k + 2] - mu, d3 = h[k + 3] - mu;
    h[k] = d0; h[k + 1] = d1; h[k + 2] = d2; h[k + 3] = d3;
    q0 = fmaf(d0, d0, q0); q1 = fmaf(d1, d1, q1);
    q2 = fmaf(d2, d2, q2); q3 = fmaf(d3, d3, q3);
  }
  float inv = rsqrtf(((q0 + q1) + (q2 + q3)) * (1.f / 64.f) + 1e-5f);
  #pragma unroll
  for (int jb = 0; jb < 3; ++jb) {
    float acc[16];
    #pragma unroll
    for (int j = 0; j < 16; ++j) acc[j] = 0.f;
    #pragma unroll
    for (int k = 0; k < HID; ++k) {
      float d = h[k];
      #pragma unroll
      for (int j = 0; j < 16; ++j) acc[j] = fmaf(d, gL[k * DOUT + jb * 16 + j], acc[j]);
    }
    #pragma unroll
    for (int j = 0; j < 16; ++j)
      acc[j] = fmaxf(fmaf(inv, acc[j], cj[jb * 16 + j]), 0.f);
    // wave-level elementwise max across 64 lanes
    #pragma unroll
    for (int m = 1; m < 64; m <<= 1) {
      #pragma unroll
      for (int j = 0; j < 16; ++j) acc[j] = fmaxf(acc[j], __shfl_xor(acc[j], m));
    }
    if ((t & 63) == 0) {
      #pragma unroll
      for (int j = 0; j < 16; ++j)
        atomicMax(&lmax[jb * 16 + j], __float_as_int(acc[j]));
    }
  }
  __syncthreads();
  if (t < DOUT) atomicMax((int*)&dout[t], lmax[t]);
}

extern "C" void kernel_launch(void* const* d_in, const int* in_sizes, int n_in,
                              void* d_out, int out_size, void* d_ws, size_t ws_size,
                              hipStream_t stream) {
  const float* x = (const float*)d_in[0];
  const int* ei = (const int*)d_in[1];
  int N = in_sizes[0] / 6;
  int E = in_sizes[1] / 2;
  const int* src = ei;
  const int* dst = ei + E;

  const float *W[3], *b[3], *g[3], *be[3], *L[3], *lb[3];
  for (int l = 0; l < 3; ++l) {
    W[l]  = (const float*)d_in[2 + 6 * l + 0];
    b[l]  = (const float*)d_in[2 + 6 * l + 1];
    g[l]  = (const float*)d_in[2 + 6 * l + 2];
    be[l] = (const float*)d_in[2 + 6 * l + 3];
    L[l]  = (const float*)d_in[2 + 6 * l + 4];
    lb[l] = (const float*)d_in[2 + 6 * l + 5];
  }

  char* p = (char*)d_ws;
  auto alloc = [&](size_t bytes) {
    char* r = p;
    p += (bytes + 255) & ~size_t(255);
    return r;
  };
  int* row_start   = (int*)alloc(sizeof(int) * (size_t)(N + 1));
  int* csr_src     = (int*)alloc(sizeof(int) * E);
  float* dinv      = (float*)alloc(sizeof(float) * N);
  int* bsize       = (int*)alloc(sizeof(int) * NBMAX);
  int* bucket_base = (int*)alloc(sizeof(int) * (NBMAX + 1));
  int* bucket_cur  = (int*)alloc(sizeof(int) * NBMAX);
  float* gL1     = (float*)alloc(sizeof(float) * 64 * 12);
  float* cj1     = (float*)alloc(sizeof(float) * 12);
  float* gL2     = (float*)alloc(sizeof(float) * 64 * 24);
  float* cj2     = (float*)alloc(sizeof(float) * 24);
  float* gL3     = (float*)alloc(sizeof(float) * 64 * 48);
  float* cj3     = (float*)alloc(sizeof(float) * 48);
  float* y1      = (float*)alloc(sizeof(float) * (size_t)N * 8);
  float* y2      = (float*)alloc(sizeof(float) * (size_t)N * 16);
  size_t y3_bytes = sizeof(float) * (size_t)N * 32;
  size_t part_bytes = sizeof(unsigned) * (size_t)E;
  float* y3      = (float*)alloc(y3_bytes > part_bytes ? y3_bytes : part_bytes);
  float* aggb    = (float*)alloc(sizeof(float) * (size_t)N * 32);
  unsigned* part = (unsigned*)y3;  // setup-phase only; y3 first written by layer-2 fpost

  float* dout = (float*)d_out;

  const int tpb = 256;
  int nbk = (N + BSIZE - 1) >> BSHIFT;  // 196 buckets

  k_init_prep<<<(5460 + tpb - 1) / tpb, tpb, 0, stream>>>(
      dout, out_size, bsize, nbk,
      g[0], be[0], L[0], lb[0], g[1], be[1], L[1], lb[1], g[2], be[2], L[2], lb[2],
      gL1, cj1, gL2, cj2, gL3, cj3);
  k_hist<<<200, 256, 0, stream>>>(dst, E, bsize);
  k_bscan<<<1, 256, 0, stream>>>(bsize, nbk, E, N, bucket_base, bucket_cur, row_start);
  k_part<<<(E + EPB - 1) / EPB, 256, 0, stream>>>(src, dst, E, bucket_cur, part);
  k_bucket<<<nbk, BSIZE, 0, stream>>>(part, bucket_base, x, N, row_start, dinv, y1, csr_src);

  int rb = (N + 3) / 4;      // k_agg: 4 node-waves per 256-thread block
  int rb64 = (N + 63) / 64;  // k_fpost: 64 rows per 64-thread block
  int rb256 = (N + 255) / 256;

  // layer 1: y1[N,8] -> agg -> fpost -> y2[N,16] (pre-scaled by dinv)
  k_agg<8, 3, 4><<<rb, 256, 0, stream>>>(y1, row_start, csr_src, aggb, N);
  k_fpost<6, 12, 8, 16><<<rb64, 64, 0, stream>>>(aggb, dinv, W[0], b[0], gL1, cj1, y2, N);

  // layer 2: y2 -> agg -> fpost -> y3[N,32] (pre-scaled)
  k_agg<16, 4, 8><<<rb, 256, 0, stream>>>(y2, row_start, csr_src, aggb, N);
  k_fpost<12, 24, 16, 32><<<rb64, 64, 0, stream>>>(aggb, dinv, W[1], b[1], gL2, cj2, y3, N);

  // layer 3: y3 -> agg -> fused fpost+colmax -> d_out (no out3 materialization)
  k_agg<32, 5, 16><<<rb, 256, 0, stream>>>(y3, row_start, csr_src, aggb, N);
  k_fpost3<<<rb256, 256, 0, stream>>>(aggb, dinv, W[2], b[2], gL3, cj3, dout, N);
}

// Round 12
// 348.596 us; speedup vs baseline: 1.0091x; 1.0091x over previous
//
#include <hip/hip_runtime.h>

constexpr int HID = 64;
constexpr int BSHIFT = 9;            // bucket = dst >> 9 (512 nodes per bucket)
constexpr int BSIZE = 1 << BSHIFT;   // 512
constexpr int NBMAX = 256;           // max buckets (N=100k -> 196)
constexpr int EPB = 4096;            // edges per k_part block

// Merged init + weight-prep: gL[k][j] = g[k]*L[k][j]; cj[j] = lb[j] + sum_k be[k]*L[k][j].
__global__ void k_init_prep(float* __restrict__ out, int d, int* __restrict__ bsize, int nb,
                            const float* __restrict__ g1, const float* __restrict__ be1,
                            const float* __restrict__ L1, const float* __restrict__ lb1,
                            const float* __restrict__ g2, const float* __restrict__ be2,
                            const float* __restrict__ L2, const float* __restrict__ lb2,
                            const float* __restrict__ g3, const float* __restrict__ be3,
                            const float* __restrict__ L3, const float* __restrict__ lb3,
                            float* __restrict__ gL1, float* __restrict__ cj1,
                            float* __restrict__ gL2, float* __restrict__ cj2,
                            float* __restrict__ gL3, float* __restrict__ cj3) {
  int t = blockIdx.x * blockDim.x + threadIdx.x;
  if (t < d) out[t] = 0.f;
  if (t < nb) bsize[t] = 0;
  if (t < 768) gL1[t] = g1[t / 12] * L1[t];
  else if (t < 768 + 1536) { int i = t - 768;  gL2[i] = g2[i / 24] * L2[i]; }
  else if (t < 2304 + 3072) { int i = t - 2304; gL3[i] = g3[i / 48] * L3[i]; }
  else if (t < 5376 + 84) {
    int i = t - 5376;
    if (i < 12) {
      float s = lb1[i];
      for (int k = 0; k < HID; ++k) s += be1[k] * L1[k * 12 + i];
      cj1[i] = s;
    } else if (i < 36) {
      int j = i - 12;
      float s = lb2[j];
      for (int k = 0; k < HID; ++k) s += be2[k] * L2[k * 24 + j];
      cj2[j] = s;
    } else {
      int j = i - 36;
      float s = lb3[j];
      for (int k = 0; k < HID; ++k) s += be3[k] * L3[k * 48 + j];
      cj3[j] = s;
    }
  }
}

// Bucket histogram: LDS-aggregated, ~grid*196 global atomics total.
__global__ __launch_bounds__(256)
void k_hist(const int* __restrict__ dst, int E, int* __restrict__ bsize) {
  __shared__ int l[NBMAX];
  int t = threadIdx.x;
  for (int i = t; i < NBMAX; i += 256) l[i] = 0;
  __syncthreads();
  int nq = E >> 2;
  const int4* d4 = (const int4*)dst;
  for (int q = blockIdx.x * 256 + t; q < nq; q += gridDim.x * 256) {
    int4 d = d4[q];
    atomicAdd(&l[d.x >> BSHIFT], 1);
    atomicAdd(&l[d.y >> BSHIFT], 1);
    atomicAdd(&l[d.z >> BSHIFT], 1);
    atomicAdd(&l[d.w >> BSHIFT], 1);
  }
  if (blockIdx.x == 0) {
    for (int e = (nq << 2) + t; e < E; e += 256) atomicAdd(&l[dst[e] >> BSHIFT], 1);
  }
  __syncthreads();
  for (int i = t; i < NBMAX; i += 256) if (l[i]) atomicAdd(&bsize[i], l[i]);
}

// Scan 196 bucket sizes -> bucket_base / bucket_cur; sentinels.
__global__ __launch_bounds__(256)
void k_bscan(const int* __restrict__ bsize, int nbk, int E, int N,
             int* __restrict__ bucket_base, int* __restrict__ bucket_cur,
             int* __restrict__ row_start) {
  __shared__ int sm[256];
  int t = threadIdx.x;
  int v = (t < nbk) ? bsize[t] : 0;
  sm[t] = v;
  __syncthreads();
  for (int off = 1; off < 256; off <<= 1) {
    int u = (t >= off) ? sm[t - off] : 0;
    __syncthreads();
    sm[t] += u;
    __syncthreads();
  }
  if (t < nbk) {
    int base = sm[t] - v;
    bucket_base[t] = base;
    bucket_cur[t] = base;
  }
  if (t == 0) { bucket_base[nbk] = E; row_start[N] = E; }
}

// Partition edges into dst-buckets; entry packed as (src<<9)|(dst&511) -> 4B.
__global__ __launch_bounds__(256)
void k_part(const int* __restrict__ src, const int* __restrict__ dst, int E,
            int* __restrict__ bucket_cur, unsigned* __restrict__ part) {
  __shared__ int lcnt[NBMAX];
  __shared__ int lcur[NBMAX];
  int t = threadIdx.x;
  int base = blockIdx.x * EPB;
  for (int i = t; i < NBMAX; i += 256) lcnt[i] = 0;
  __syncthreads();
  bool full = (base + EPB) <= E;
  int4 sv[4], dv[4];
  if (full) {
    const int4* src4 = (const int4*)src;
    const int4* dst4 = (const int4*)dst;
    #pragma unroll
    for (int u = 0; u < 4; ++u) {
      int q = (base >> 2) + u * 256 + t;
      sv[u] = src4[q];
      dv[u] = dst4[q];
    }
    #pragma unroll
    for (int u = 0; u < 4; ++u) {
      atomicAdd(&lcnt[dv[u].x >> BSHIFT], 1);
      atomicAdd(&lcnt[dv[u].y >> BSHIFT], 1);
      atomicAdd(&lcnt[dv[u].z >> BSHIFT], 1);
      atomicAdd(&lcnt[dv[u].w >> BSHIFT], 1);
    }
  } else {
    for (int u = 0; u < 16; ++u) {
      int e = base + u * 256 + t;
      if (e < E) atomicAdd(&lcnt[dst[e] >> BSHIFT], 1);
    }
  }
  __syncthreads();
  for (int i = t; i < NBMAX; i += 256)
    lcur[i] = lcnt[i] ? atomicAdd(&bucket_cur[i], lcnt[i]) : 0;
  __syncthreads();
  if (full) {
    #pragma unroll
    for (int u = 0; u < 4; ++u) {
      int pos;
      pos = atomicAdd(&lcur[dv[u].x >> BSHIFT], 1);
      part[pos] = ((unsigned)sv[u].x << BSHIFT) | ((unsigned)dv[u].x & (BSIZE - 1));
      pos = atomicAdd(&lcur[dv[u].y >> BSHIFT], 1);
      part[pos] = ((unsigned)sv[u].y << BSHIFT) | ((unsigned)dv[u].y & (BSIZE - 1));
      pos = atomicAdd(&lcur[dv[u].z >> BSHIFT], 1);
      part[pos] = ((unsigned)sv[u].z << BSHIFT) | ((unsigned)dv[u].z & (BSIZE - 1));
      pos = atomicAdd(&lcur[dv[u].w >> BSHIFT], 1);
      part[pos] = ((unsigned)sv[u].w << BSHIFT) | ((unsigned)dv[u].w & (BSIZE - 1));
    }
  } else {
    for (int u = 0; u < 16; ++u) {
      int e = base + u * 256 + t;
      if (e < E) {
        int s = src[e], d = dst[e];
        int pos = atomicAdd(&lcur[d >> BSHIFT], 1);
        part[pos] = ((unsigned)s << BSHIFT) | ((unsigned)d & (BSIZE - 1));
      }
    }
  }
}

// Per-bucket: LDS per-node histogram + LDS scan -> row_start/dinv/y1, then
// LDS-cursor scatter -> csr_src. Zero per-node GLOBAL atomics.
__global__ __launch_bounds__(512)
void k_bucket(const unsigned* __restrict__ part, const int* __restrict__ bucket_base,
              const float* __restrict__ x, int N,
              int* __restrict__ row_start, float* __restrict__ dinv,
              float* __restrict__ y1, int* __restrict__ csr_src) {
  __shared__ int hist[BSIZE];
  __shared__ int cur[BSIZE];
  int b = blockIdx.x;
  int t = threadIdx.x;
  int base = bucket_base[b];
  int end = bucket_base[b + 1];
  hist[t] = 0;
  __syncthreads();
  for (int e = base + t; e < end; e += BSIZE)
    atomicAdd(&hist[part[e] & (BSIZE - 1)], 1);
  __syncthreads();
  int c = hist[t];
  for (int off = 1; off < BSIZE; off <<= 1) {
    int u = (t >= off) ? hist[t - off] : 0;
    __syncthreads();
    hist[t] += u;
    __syncthreads();
  }
  int gpos = base + hist[t] - c;  // exclusive prefix + bucket base
  cur[t] = gpos;
  int node = (b << BSHIFT) + t;
  if (node < N) {
    row_start[node] = gpos;
    float di = rsqrtf((float)(c + 1));
    dinv[node] = di;
    const float* xr = x + (size_t)node * 6;
    float4* yp = (float4*)(y1 + (size_t)node * 8);
    yp[0] = make_float4(xr[0] * di, xr[1] * di, xr[2] * di, xr[3] * di);
    yp[1] = make_float4(xr[4] * di, xr[5] * di, 0.f, 0.f);
  }
  __syncthreads();
  for (int e = base + t; e < end; e += BSIZE) {
    unsigned u = part[e];
    int pos = atomicAdd(&cur[u & (BSIZE - 1)], 1);
    csr_src[pos] = (int)(u >> BSHIFT);
  }
}

// Gather-aggregate of pre-scaled features y [N][F] (F=8/16/32 padded).
// U*C = 32 edges issued per round -> deg<=32 rows (>99.9%) finish in ONE
// latency round. Clamped tail loads hit the same cache line (same s, f).
template<int F, int LOGF, int U>
__global__ __launch_bounds__(256)
void k_agg(const float* __restrict__ y, const int* __restrict__ row_start,
           const int* __restrict__ csr, float* __restrict__ agg, int N) {
  constexpr int C = 64 / F;
  int wid = (blockIdx.x * blockDim.x + threadIdx.x) >> 6;
  if (wid >= N) return;
  int lane = threadIdx.x & 63;
  int es = lane >> LOGF;
  int f = lane & (F - 1);
  int e0 = row_start[wid], e1 = row_start[wid + 1];
  float acc = 0.f;
  for (int e = e0 + es; e < e1; e += U * C) {
    float v[U];
    #pragma unroll
    for (int u = 0; u < U; ++u) {
      int ee = e + u * C;
      int ec = min(ee, e1 - 1);
      int s = csr[ec];
      float val = y[(size_t)s * F + f];
      v[u] = (ee < e1) ? val : 0.f;
    }
    #pragma unroll
    for (int u = 0; u < U; ++u) acc += v[u];
  }
  #pragma unroll
  for (int m = F; m < 64; m <<= 1) acc += __shfl_xor(acc, m);
  if (lane < F) {
    acc += y[(size_t)wid * F + f];  // self loop (y already *dinv[self])
    agg[(size_t)wid * F + f] = acc;
  }
}

// Fused per-row epilogue (layers 1-2): h = relu(dinv*(agg@W) + b); LN in-reg;
// out = relu(inv*(d@gL) + cj) * dinv (pre-scaled for next gather).
template<int DIN, int DOUT, int FIN, int FOUT>
__global__ __launch_bounds__(64)
void k_fpost(const float* __restrict__ agg, const float* __restrict__ dinv,
             const float* __restrict__ W, const float* __restrict__ bb,
             const float* __restrict__ gL, const float* __restrict__ cj,
             float* __restrict__ yout, int N) {
  int row = blockIdx.x * 64 + threadIdx.x;
  bool act = row < N;
  int r = act ? row : N - 1;
  const float4* ap = (const float4*)(agg + (size_t)r * FIN);
  float di = dinv[r];
  float h[HID];
  #pragma unroll
  for (int j = 0; j < HID; ++j) h[j] = 0.f;
  // interleave agg chunks with GEMM: only 4 a-floats live at once
  #pragma unroll
  for (int c = 0; c < DIN / 4; ++c) {
    float4 t4 = ap[c];
    float av[4] = {t4.x, t4.y, t4.z, t4.w};
    #pragma unroll
    for (int u = 0; u < 4; ++u) {
      float v = av[u];
      int k = 4 * c + u;
      #pragma unroll
      for (int j = 0; j < HID; ++j) h[j] = fmaf(v, W[k * HID + j], h[j]);
    }
  }
  if constexpr (DIN % 4 != 0) {
    // DIN=6: tail 2 elements
    float2 t2 = ((const float2*)ap)[DIN / 2 - 1];
    float av[2] = {t2.x, t2.y};
    #pragma unroll
    for (int u = 0; u < 2; ++u) {
      float v = av[u];
      int k = (DIN / 4) * 4 + u;
      #pragma unroll
      for (int j = 0; j < HID; ++j) h[j] = fmaf(v, W[k * HID + j], h[j]);
    }
  }
  float s0 = 0.f, s1 = 0.f, s2 = 0.f, s3 = 0.f;
  #pragma unroll
  for (int k = 0; k < HID; k += 4) {
    h[k]     = fmaxf(fmaf(h[k],     di, bb[k]),     0.f); s0 += h[k];
    h[k + 1] = fmaxf(fmaf(h[k + 1], di, bb[k + 1]), 0.f); s1 += h[k + 1];
    h[k + 2] = fmaxf(fmaf(h[k + 2], di, bb[k + 2]), 0.f); s2 += h[k + 2];
    h[k + 3] = fmaxf(fmaf(h[k + 3], di, bb[k + 3]), 0.f); s3 += h[k + 3];
  }
  float mu = ((s0 + s1) + (s2 + s3)) * (1.f / 64.f);
  float q0 = 0.f, q1 = 0.f, q2 = 0.f, q3 = 0.f;
  #pragma unroll
  for (int k = 0; k < HID; k += 4) {
    float d0 = h[k] - mu, d1 = h[k + 1] - mu, d2 = h[k + 2] - mu, d3 = h[k + 3] - mu;
    h[k] = d0; h[k + 1] = d1; h[k + 2] = d2; h[k + 3] = d3;
    q0 = fmaf(d0, d0, q0); q1 = fmaf(d1, d1, q1);
    q2 = fmaf(d2, d2, q2); q3 = fmaf(d3, d3, q3);
  }
  float inv = rsqrtf(((q0 + q1) + (q2 + q3)) * (1.f / 64.f) + 1e-5f);
  float acc[DOUT];
  #pragma unroll
  for (int j = 0; j < DOUT; ++j) acc[j] = 0.f;
  #pragma unroll
  for (int k = 0; k < HID; ++k) {
    float d = h[k];
    #pragma unroll
    for (int j = 0; j < DOUT; ++j) acc[j] = fmaf(d, gL[k * DOUT + j], acc[j]);
  }
  if (act) {
    float4* op = (float4*)(yout + (size_t)row * FOUT);
    #pragma unroll
    for (int c = 0; c < FOUT / 4; ++c) {
      float o[4];
      #pragma unroll
      for (int u = 0; u < 4; ++u) {
        int j = 4 * c + u;
        o[u] = (j < DOUT) ? fmaxf(fmaf(inv, acc[j], cj[j]), 0.f) * di : 0.f;
      }
      op[c] = make_float4(o[0], o[1], o[2], o[3]);
    }
  }
}

// Layer-3 epilogue + per-block column-max partials. 64-thread block (the shape
// the allocator treats sanely — 256-thread version was pinned at 60 VGPR and
// spilled h[64], r9/r11 both 53-57us). waves_per_eu(1,2) -> up to 256 VGPR;
// grid only supplies ~6 waves/CU so the occupancy cap costs nothing.
__global__ __launch_bounds__(64)
__attribute__((amdgpu_waves_per_eu(1, 2)))
void k_fpost3w(const float* __restrict__ agg, const float* __restrict__ dinv,
               const float* __restrict__ W, const float* __restrict__ bb,
               const float* __restrict__ gL, const float* __restrict__ cj,
               float* __restrict__ pmax, int nb3, int N) {
  constexpr int DIN = 24, DOUT = 48;
  int t = threadIdx.x;
  int row = blockIdx.x * 64 + t;
  int r = min(row, N - 1);  // tail duplicates re-contribute a real row: max-safe
  const float4* ap = (const float4*)(agg + (size_t)r * 32);
  float di = dinv[r];
  float h[HID];
  #pragma unroll
  for (int j = 0; j < HID; ++j) h[j] = 0.f;
  #pragma unroll
  for (int c = 0; c < DIN / 4; ++c) {
    float4 t4 = ap[c];
    float av[4] = {t4.x, t4.y, t4.z, t4.w};
    #pragma unroll
    for (int u = 0; u < 4; ++u) {
      float v = av[u];
      int k = 4 * c + u;
      #pragma unroll
      for (int j = 0; j < HID; ++j) h[j] = fmaf(v, W[k * HID + j], h[j]);
    }
  }
  float s0 = 0.f, s1 = 0.f, s2 = 0.f, s3 = 0.f;
  #pragma unroll
  for (int k = 0; k < HID; k += 4) {
    h[k]     = fmaxf(fmaf(h[k],     di, bb[k]),     0.f); s0 += h[k];
    h[k + 1] = fmaxf(fmaf(h[k + 1], di, bb[k + 1]), 0.f); s1 += h[k + 1];
    h[k + 2] = fmaxf(fmaf(h[k + 2], di, bb[k + 2]), 0.f); s2 += h[k + 2];
    h[k + 3] = fmaxf(fmaf(h[k + 3], di, bb[k + 3]), 0.f); s3 += h[k + 3];
  }
  float mu = ((s0 + s1) + (s2 + s3)) * (1.f / 64.f);
  float q0 = 0.f, q1 = 0.f, q2 = 0.f, q3 = 0.f;
  #pragma unroll
  for (int k = 0; k < HID; k += 4) {
    float d0 = h[k] - mu, d1 = h[k + 1] - mu, d2 = h[k + 2] - mu, d3 = h[k + 3] - mu;
    h[k] = d0; h[k + 1] = d1; h[k + 2] = d2; h[k + 3] = d3;
    q0 = fmaf(d0, d0, q0); q1 = fmaf(d1, d1, q1);
    q2 = fmaf(d2, d2, q2); q3 = fmaf(d3, d3, q3);
  }
  float inv = rsqrtf(((q0 + q1) + (q2 + q3)) * (1.f / 64.f) + 1e-5f);
  float acc[DOUT];
  #pragma unroll
  for (int j = 0; j < DOUT; ++j) acc[j] = 0.f;
  #pragma unroll
  for (int k = 0; k < HID; ++k) {
    float d = h[k];
    #pragma unroll
    for (int j = 0; j < DOUT; ++j) acc[j] = fmaf(d, gL[k * DOUT + j], acc[j]);
  }
  #pragma unroll
  for (int j = 0; j < DOUT; ++j)
    acc[j] = fmaxf(fmaf(inv, acc[j], cj[j]), 0.f);
  // wave elementwise max (static indices) -> all lanes hold the block max
  #pragma unroll
  for (int m = 1; m < 64; m <<= 1) {
    #pragma unroll
    for (int j = 0; j < DOUT; ++j) acc[j] = fmaxf(acc[j], __shfl_xor(acc[j], m));
  }
  if (t == 0) {
    #pragma unroll
    for (int j = 0; j < DOUT; ++j) pmax[j * nb3 + blockIdx.x] = acc[j];
  }
}

// Final column reduce: block j reduces pmax[j][0..nb3) (contiguous) -> dout[j].
__global__ __launch_bounds__(256)
void k_redmax(const float* __restrict__ pmax, int nb3, float* __restrict__ dout) {
  __shared__ float sm[256];
  int j = blockIdx.x;
  int t = threadIdx.x;
  float m = 0.f;  // post-relu values are >= 0
  for (int i = t; i < nb3; i += 256) m = fmaxf(m, pmax[j * nb3 + i]);
  sm[t] = m;
  __syncthreads();
  for (int off = 128; off > 0; off >>= 1) {
    if (t < off) sm[t] = fmaxf(sm[t], sm[t + off]);
    __syncthreads();
  }
  if (t == 0) dout[j] = sm[0];
}

extern "C" void kernel_launch(void* const* d_in, const int* in_sizes, int n_in,
                              void* d_out, int out_size, void* d_ws, size_t ws_size,
                              hipStream_t stream) {
  const float* x = (const float*)d_in[0];
  const int* ei = (const int*)d_in[1];
  int N = in_sizes[0] / 6;
  int E = in_sizes[1] / 2;
  const int* src = ei;
  const int* dst = ei + E;

  const float *W[3], *b[3], *g[3], *be[3], *L[3], *lb[3];
  for (int l = 0; l < 3; ++l) {
    W[l]  = (const float*)d_in[2 + 6 * l + 0];
    b[l]  = (const float*)d_in[2 + 6 * l + 1];
    g[l]  = (const float*)d_in[2 + 6 * l + 2];
    be[l] = (const float*)d_in[2 + 6 * l + 3];
    L[l]  = (const float*)d_in[2 + 6 * l + 4];
    lb[l] = (const float*)d_in[2 + 6 * l + 5];
  }

  char* p = (char*)d_ws;
  auto alloc = [&](size_t bytes) {
    char* r = p;
    p += (bytes + 255) & ~size_t(255);
    return r;
  };
  int nb3 = (N + 63) / 64;  // k_fpost3w blocks
  int* row_start   = (int*)alloc(sizeof(int) * (size_t)(N + 1));
  int* csr_src     = (int*)alloc(sizeof(int) * E);
  float* dinv      = (float*)alloc(sizeof(float) * N);
  int* bsize       = (int*)alloc(sizeof(int) * NBMAX);
  int* bucket_base = (int*)alloc(sizeof(int) * (NBMAX + 1));
  int* bucket_cur  = (int*)alloc(sizeof(int) * NBMAX);
  float* gL1     = (float*)alloc(sizeof(float) * 64 * 12);
  float* cj1     = (float*)alloc(sizeof(float) * 12);
  float* gL2     = (float*)alloc(sizeof(float) * 64 * 24);
  float* cj2     = (float*)alloc(sizeof(float) * 24);
  float* gL3     = (float*)alloc(sizeof(float) * 64 * 48);
  float* cj3     = (float*)alloc(sizeof(float) * 48);
  float* y1      = (float*)alloc(sizeof(float) * (size_t)N * 8);
  float* y2      = (float*)alloc(sizeof(float) * (size_t)N * 16);
  size_t y3_bytes = sizeof(float) * (size_t)N * 32;
  size_t part_bytes = sizeof(unsigned) * (size_t)E;
  float* y3      = (float*)alloc(y3_bytes > part_bytes ? y3_bytes : part_bytes);
  float* aggb    = (float*)alloc(sizeof(float) * (size_t)N * 32);
  float* pmax    = (float*)alloc(sizeof(float) * 48 * (size_t)nb3);
  unsigned* part = (unsigned*)y3;  // setup-phase only; y3 first written by layer-2 fpost

  float* dout = (float*)d_out;

  const int tpb = 256;
  int nbk = (N + BSIZE - 1) >> BSHIFT;  // 196 buckets

  k_init_prep<<<(5460 + tpb - 1) / tpb, tpb, 0, stream>>>(
      dout, out_size, bsize, nbk,
      g[0], be[0], L[0], lb[0], g[1], be[1], L[1], lb[1], g[2], be[2], L[2], lb[2],
      gL1, cj1, gL2, cj2, gL3, cj3);
  k_hist<<<200, 256, 0, stream>>>(dst, E, bsize);
  k_bscan<<<1, 256, 0, stream>>>(bsize, nbk, E, N, bucket_base, bucket_cur, row_start);
  k_part<<<(E + EPB - 1) / EPB, 256, 0, stream>>>(src, dst, E, bucket_cur, part);
  k_bucket<<<nbk, BSIZE, 0, stream>>>(part, bucket_base, x, N, row_start, dinv, y1, csr_src);

  int rb = (N + 3) / 4;      // k_agg: 4 node-waves per 256-thread block
  int rb64 = (N + 63) / 64;  // k_fpost: 64 rows per 64-thread block

  // layer 1: y1[N,8] -> agg -> fpost -> y2[N,16] (pre-scaled by dinv)
  k_agg<8, 3, 4><<<rb, 256, 0, stream>>>(y1, row_start, csr_src, aggb, N);
  k_fpost<6, 12, 8, 16><<<rb64, 64, 0, stream>>>(aggb, dinv, W[0], b[0], gL1, cj1, y2, N);

  // layer 2: y2 -> agg -> fpost -> y3[N,32] (pre-scaled)
  k_agg<16, 4, 8><<<rb, 256, 0, stream>>>(y2, row_start, csr_src, aggb, N);
  k_fpost<12, 24, 16, 32><<<rb64, 64, 0, stream>>>(aggb, dinv, W[1], b[1], gL2, cj2, y3, N);

  // layer 3: y3 -> agg -> epilogue w/ per-block colmax partials -> reduce
  k_agg<32, 5, 16><<<rb, 256, 0, stream>>>(y3, row_start, csr_src, aggb, N);
  k_fpost3w<<<nb3, 64, 0, stream>>>(aggb, dinv, W[2], b[2], gL3, cj3, pmax, nb3, N);
  k_redmax<<<48, 256, 0, stream>>>(pmax, nb3, dout);
}